// Round 7
// baseline (1364.592 us; speedup 1.0000x reference)
//
#include <hip/hip_runtime.h>
#include <hip/hip_fp16.h>

// GraphEncoder: node linear; 3x GINEConv(eps=0, nn=Linear+LeakyReLU); skip; head Linear+LayerNorm.
// R7: gather edge-MLP via v_dot2_f32_f16 (fp16 We pairs, fp32 accum) -> ~3x fewer VALU inst/edge.
//     Matvec kernels register-tiled 4 nodes x 4 channels (float4 W loads, LDS broadcasts).
// edge_index arrives as int32 (harness converts int64 inputs).
constexpr int N      = 100000;
constexpr int E      = 1600000;
constexpr int F_IN   = 64;
constexpr int F_EDGE = 16;
constexpr int H      = 128;
constexpr int NB     = (N + 255) / 256;     // 391 scan blocks
constexpr float NEG  = 0.01f;
constexpr float EPS  = 1e-5f;

typedef _Float16 hv2 __attribute__((ext_vector_type(2)));

// ================= CSR build =================
__global__ __launch_bounds__(256) void k_zero(int* __restrict__ p, int n) {
  int i = blockIdx.x * 256 + threadIdx.x;
  if (i < n) p[i] = 0;
}

__global__ __launch_bounds__(256) void k_hist(const int* __restrict__ eidx, int* __restrict__ deg) {
  int i = blockIdx.x * 256 + threadIdx.x;
  if (i < E) atomicAdd(&deg[eidx[E + i]], 1);
}

__global__ __launch_bounds__(256) void k_scan_block(const int* __restrict__ deg,
    int* __restrict__ excl, int* __restrict__ bsum) {
  __shared__ int s[256];
  int t = threadIdx.x, i = blockIdx.x * 256 + t;
  int v = (i < N) ? deg[i] : 0;
  s[t] = v; __syncthreads();
#pragma unroll
  for (int off = 1; off < 256; off <<= 1) {
    int u = (t >= off) ? s[t - off] : 0;
    __syncthreads();
    s[t] += u;
    __syncthreads();
  }
  if (i < N) excl[i] = s[t] - v;
  if (t == 255) bsum[blockIdx.x] = s[255];
}

__global__ __launch_bounds__(512) void k_scan_top(const int* __restrict__ bsum, int* __restrict__ boff) {
  __shared__ int s[512];
  int t = threadIdx.x;
  int v = (t < NB) ? bsum[t] : 0;
  s[t] = v; __syncthreads();
#pragma unroll
  for (int off = 1; off < 512; off <<= 1) {
    int u = (t >= off) ? s[t - off] : 0;
    __syncthreads();
    s[t] += u;
    __syncthreads();
  }
  if (t < NB) boff[t] = s[t] - v;
}

__global__ __launch_bounds__(256) void k_scan_add(const int* __restrict__ excl,
    const int* __restrict__ boff, int* __restrict__ rowptr, int* __restrict__ cursor) {
  int i = blockIdx.x * 256 + threadIdx.x;
  if (i < N) {
    int r = excl[i] + boff[i >> 8];
    rowptr[i] = r;
    cursor[i] = r;
  }
}

// scatter: CSR-slot src index + edge_attr row converted to fp16 (2x uint4 = 32B/edge)
__global__ __launch_bounds__(256) void k_scatter(const int* __restrict__ eidx,
    const float* __restrict__ edge_attr, int* __restrict__ cursor,
    int* __restrict__ csr_src, uint4* __restrict__ csr_a16) {
  int i = blockIdx.x * 256 + threadIdx.x;
  if (i >= E) return;
  int d = eidx[E + i];
  int pos = atomicAdd(&cursor[d], 1);
  csr_src[pos] = eidx[i];
  const float4* ar = (const float4*)(edge_attr + (size_t)i * F_EDGE);
  float4 f0 = ar[0], f1 = ar[1], f2 = ar[2], f3 = ar[3];
  __half2 hh[8];
  hh[0] = __float22half2_rn(make_float2(f0.x, f0.y));
  hh[1] = __float22half2_rn(make_float2(f0.z, f0.w));
  hh[2] = __float22half2_rn(make_float2(f1.x, f1.y));
  hh[3] = __float22half2_rn(make_float2(f1.z, f1.w));
  hh[4] = __float22half2_rn(make_float2(f2.x, f2.y));
  hh[5] = __float22half2_rn(make_float2(f2.z, f2.w));
  hh[6] = __float22half2_rn(make_float2(f3.x, f3.y));
  hh[7] = __float22half2_rn(make_float2(f3.z, f3.w));
  const uint4* u = (const uint4*)hh;
  csr_a16[2 * (size_t)pos + 0] = u[0];
  csr_a16[2 * (size_t)pos + 1] = u[1];
}

// ================= node linear: h = x @ W_node + b  (32 nodes/block, 4n x 4c per thread) =================
__global__ __launch_bounds__(256) void k_node_linear(
    const float* __restrict__ x, const float* __restrict__ W,
    const float* __restrict__ b, float* __restrict__ h, __half* __restrict__ h16) {
  __shared__ float xs[32][F_IN];             // 8 KB
  int i0 = blockIdx.x * 32;
  {
    const float4* s4 = (const float4*)(x + (size_t)i0 * F_IN);
    float4* t4 = (float4*)xs;
#pragma unroll
    for (int r = 0; r < 2; ++r) t4[threadIdx.x + 256 * r] = s4[threadIdx.x + 256 * r];
  }
  __syncthreads();
  int c0 = (threadIdx.x & 31) * 4;
  int n0 = (threadIdx.x >> 5) * 4;
  float4 bb = *(const float4*)(b + c0);
  float4 acc[4] = {bb, bb, bb, bb};
#pragma unroll 4
  for (int k = 0; k < F_IN; ++k) {
    float4 w4 = *(const float4*)(W + k * H + c0);   // coalesced; reused by 4 nodes
#pragma unroll
    for (int j = 0; j < 4; ++j) {
      float s = xs[n0 + j][k];                      // LDS broadcast (same addr in 32 lanes)
      acc[j].x = fmaf(s, w4.x, acc[j].x);
      acc[j].y = fmaf(s, w4.y, acc[j].y);
      acc[j].z = fmaf(s, w4.z, acc[j].z);
      acc[j].w = fmaf(s, w4.w, acc[j].w);
    }
  }
#pragma unroll
  for (int j = 0; j < 4; ++j) {
    size_t idx = (size_t)(i0 + n0 + j) * H + c0;
    *(float4*)(h + idx) = acc[j];
    __half2* ph = (__half2*)(h16 + idx);
    ph[0] = __float22half2_rn(make_float2(acc[j].x, acc[j].y));
    ph[1] = __float22half2_rn(make_float2(acc[j].z, acc[j].w));
  }
}

// ================= gather: sum[i] = h[i] + sum_in relu(h16[src] + a16@We + be) =================
// 1 wave per node; lane owns channels {2*lane, 2*lane+1}; We as fp16 k-pairs -> v_dot2_f32_f16.
__device__ __forceinline__ void dot16(uint4 A0, uint4 A1,
                                      const hv2* __restrict__ wA, const hv2* __restrict__ wB,
                                      float& tx, float& ty) {
  unsigned u[8] = {A0.x, A0.y, A0.z, A0.w, A1.x, A1.y, A1.z, A1.w};
#pragma unroll
  for (int j = 0; j < 8; ++j) {
    hv2 a = __builtin_bit_cast(hv2, u[j]);
    tx = __builtin_amdgcn_fdot2(a, wA[j], tx, false);
    ty = __builtin_amdgcn_fdot2(a, wB[j], ty, false);
  }
}

__global__ __launch_bounds__(256) void k_gather(
    const int* __restrict__ rowptr, const int* __restrict__ deg,
    const int* __restrict__ csr_src, const uint4* __restrict__ csr_a16,
    const __half2* __restrict__ h16, const float* __restrict__ We,
    const float* __restrict__ be, const float* __restrict__ h,
    float* __restrict__ sum) {
  int lane = threadIdx.x & 63;
  int node = (blockIdx.x * 256 + threadIdx.x) >> 6;
  if (node >= N) return;
  int c0 = 2 * lane;
  hv2 wA[8], wB[8];                          // We columns c0,c0+1 packed as k-pairs
#pragma unroll
  for (int j = 0; j < 8; ++j) {
    hv2 a, bq;
    a[0]  = (_Float16)We[(2 * j) * H + c0];
    a[1]  = (_Float16)We[(2 * j + 1) * H + c0];
    bq[0] = (_Float16)We[(2 * j) * H + c0 + 1];
    bq[1] = (_Float16)We[(2 * j + 1) * H + c0 + 1];
    wA[j] = a; wB[j] = bq;
  }
  float2 bias = ((const float2*)be)[lane];
  float2 acc = ((const float2*)(h + (size_t)node * H))[lane];   // self term, fp32
  int p0 = rowptr[node];
  int pend = p0 + deg[node];
  int p = p0;
  for (; p + 2 <= pend; p += 2) {
    int s0 = csr_src[p];
    int s1 = csr_src[p + 1];
    __half2 g0 = h16[(size_t)s0 * 64 + lane];   // random 128B/wave
    __half2 g1 = h16[(size_t)s1 * 64 + lane];
    uint4 A0 = csr_a16[2 * (size_t)p + 0];      // sequential 64B/edge stream
    uint4 A1 = csr_a16[2 * (size_t)p + 1];
    uint4 B0 = csr_a16[2 * (size_t)p + 2];
    uint4 B1 = csr_a16[2 * (size_t)p + 3];
    float t0x = bias.x, t0y = bias.y;
    float t1x = bias.x, t1y = bias.y;
    dot16(A0, A1, wA, wB, t0x, t0y);
    dot16(B0, B1, wA, wB, t1x, t1y);
    float2 gf0 = __half22float2(g0);
    float2 gf1 = __half22float2(g1);
    acc.x += fmaxf(gf0.x + t0x, 0.f) + fmaxf(gf1.x + t1x, 0.f);
    acc.y += fmaxf(gf0.y + t0y, 0.f) + fmaxf(gf1.y + t1y, 0.f);
  }
  for (; p < pend; ++p) {
    int s = csr_src[p];
    __half2 g = h16[(size_t)s * 64 + lane];
    uint4 A0 = csr_a16[2 * (size_t)p + 0];
    uint4 A1 = csr_a16[2 * (size_t)p + 1];
    float tx = bias.x, ty = bias.y;
    dot16(A0, A1, wA, wB, tx, ty);
    float2 gf = __half22float2(g);
    acc.x += fmaxf(gf.x + tx, 0.f);
    acc.y += fmaxf(gf.y + ty, 0.f);
  }
  ((float2*)sum)[(size_t)node * 64 + lane] = acc;
}

// ================= node update: h = leaky_relu(sum @ W_conv[l] + b)  (32 nodes/block) =================
__global__ __launch_bounds__(256) void k_node_update(
    const float* __restrict__ sum, const float* __restrict__ W,
    const float* __restrict__ b, float* __restrict__ hout, __half* __restrict__ h16) {
  __shared__ float t[32][H];                 // 16 KB
  int i0 = blockIdx.x * 32;
  {
    const float4* s4 = (const float4*)(sum + (size_t)i0 * H);
    float4* t4 = (float4*)t;
#pragma unroll
    for (int r = 0; r < 4; ++r) t4[threadIdx.x + 256 * r] = s4[threadIdx.x + 256 * r];
  }
  __syncthreads();
  int c0 = (threadIdx.x & 31) * 4;
  int n0 = (threadIdx.x >> 5) * 4;
  float4 bb = *(const float4*)(b + c0);
  float4 acc[4] = {bb, bb, bb, bb};
#pragma unroll 4
  for (int k = 0; k < H; ++k) {
    float4 w4 = *(const float4*)(W + k * H + c0);   // coalesced; reused by 4 nodes
#pragma unroll
    for (int j = 0; j < 4; ++j) {
      float s = t[n0 + j][k];                       // LDS broadcast
      acc[j].x = fmaf(s, w4.x, acc[j].x);
      acc[j].y = fmaf(s, w4.y, acc[j].y);
      acc[j].z = fmaf(s, w4.z, acc[j].z);
      acc[j].w = fmaf(s, w4.w, acc[j].w);
    }
  }
#pragma unroll
  for (int j = 0; j < 4; ++j) {
    float4 a = acc[j];
    a.x = a.x >= 0.f ? a.x : NEG * a.x;
    a.y = a.y >= 0.f ? a.y : NEG * a.y;
    a.z = a.z >= 0.f ? a.z : NEG * a.z;
    a.w = a.w >= 0.f ? a.w : NEG * a.w;
    size_t idx = (size_t)(i0 + n0 + j) * H + c0;
    *(float4*)(hout + idx) = a;
    __half2* ph = (__half2*)(h16 + idx);
    ph[0] = __float22half2_rn(make_float2(a.x, a.y));
    ph[1] = __float22half2_rn(make_float2(a.z, a.w));
  }
}

// ================= head: skip recomputed; y = (skip+h)@W_head + b; LayerNorm  (8 nodes/block) =================
__global__ __launch_bounds__(256) void k_head(
    const float* __restrict__ x, const float* __restrict__ Wn,
    const float* __restrict__ bn, const float* __restrict__ hfin,
    const float* __restrict__ W, const float* __restrict__ b,
    const float* __restrict__ gamma, const float* __restrict__ beta,
    float* __restrict__ out) {
  __shared__ float xs[8][F_IN];              // 2 KB
  __shared__ float t[8][H];                  // 4 KB
  int i0 = blockIdx.x * 8;
  if (threadIdx.x < 128)
    ((float4*)xs)[threadIdx.x] = ((const float4*)(x + (size_t)i0 * F_IN))[threadIdx.x];
  __syncthreads();
  int c0 = (threadIdx.x & 31) * 4;
  int ng = threadIdx.x >> 5;                 // node within block; 32 lanes per node
  // skip = x @ W_node + b_node for (node ng, channels c0..c0+3)
  float4 sk = *(const float4*)(bn + c0);
#pragma unroll 4
  for (int k = 0; k < F_IN; ++k) {
    float4 w4 = *(const float4*)(Wn + k * H + c0);
    float s = xs[ng][k];                     // LDS broadcast
    sk.x = fmaf(s, w4.x, sk.x);
    sk.y = fmaf(s, w4.y, sk.y);
    sk.z = fmaf(s, w4.z, sk.z);
    sk.w = fmaf(s, w4.w, sk.w);
  }
  float4 hf = *(const float4*)(hfin + (size_t)(i0 + ng) * H + c0);
  sk.x += hf.x; sk.y += hf.y; sk.z += hf.z; sk.w += hf.w;
  *(float4*)&t[ng][c0] = sk;
  __syncthreads();
  float4 acc = *(const float4*)(b + c0);
#pragma unroll 4
  for (int k = 0; k < H; ++k) {
    float4 w4 = *(const float4*)(W + k * H + c0);
    float s = t[ng][k];                      // LDS broadcast
    acc.x = fmaf(s, w4.x, acc.x);
    acc.y = fmaf(s, w4.y, acc.y);
    acc.z = fmaf(s, w4.z, acc.z);
    acc.w = fmaf(s, w4.w, acc.w);
  }
  // LayerNorm across the 32 lanes holding this node's 128 channels
  float S  = acc.x + acc.y + acc.z + acc.w;
  float S2 = acc.x * acc.x + acc.y * acc.y + acc.z * acc.z + acc.w * acc.w;
#pragma unroll
  for (int off = 16; off > 0; off >>= 1) {
    S  += __shfl_down(S, off, 32);
    S2 += __shfl_down(S2, off, 32);
  }
  S  = __shfl(S, 0, 32);
  S2 = __shfl(S2, 0, 32);
  float mu  = S * (1.f / H);
  float var = S2 * (1.f / H) - mu * mu;
  float inv = rsqrtf(var + EPS);
  float4 g4 = *(const float4*)(gamma + c0);
  float4 b4 = *(const float4*)(beta + c0);
  float4 o;
  o.x = (acc.x - mu) * inv * g4.x + b4.x;
  o.y = (acc.y - mu) * inv * g4.y + b4.y;
  o.z = (acc.z - mu) * inv * g4.z + b4.z;
  o.w = (acc.w - mu) * inv * g4.w + b4.w;
  *(float4*)(out + (size_t)(i0 + ng) * H + c0) = o;
}

extern "C" void kernel_launch(void* const* d_in, const int* in_sizes, int n_in,
                              void* d_out, int out_size, void* d_ws, size_t ws_size,
                              hipStream_t stream) {
  const float* x         = (const float*)d_in[0];
  const float* edge_attr = (const float*)d_in[1];
  const int*   eidx      = (const int*)d_in[2];      // int32 (harness-converted)
  const float* W_node    = (const float*)d_in[3];
  const float* b_node    = (const float*)d_in[4];
  const float* W_edge    = (const float*)d_in[5];
  const float* b_edge    = (const float*)d_in[6];
  const float* W_conv    = (const float*)d_in[7];    // [3,128,128]
  const float* b_conv    = (const float*)d_in[8];    // [3,128]
  const float* W_head    = (const float*)d_in[9];
  const float* b_head    = (const float*)d_in[10];
  const float* gamma     = (const float*)d_in[11];
  const float* beta      = (const float*)d_in[12];
  float* out = (float*)d_out;

  // ---- workspace layout (~136.2 MB) ----
  size_t S = (size_t)N * H;                  // 12.8M floats = 51.2 MB
  float*   h       = (float*)d_ws;           // 51.2 MB
  uint4*   csr_a16 = (uint4*)(h + S);        // 51.2 MB (E x 32B)
  __half*  h16     = (__half*)(csr_a16 + 2 * (size_t)E);  // 25.6 MB
  int*     csr_src = (int*)(h16 + S);        // 6.4 MB
  int*     deg     = csr_src + E;
  int*     excl    = deg + N;
  int*     rowptr  = excl + N;
  int*     cursor  = rowptr + N;
  int*     bsum    = cursor + N;
  int*     boff    = bsum + 512;
  float*   sum     = out;                    // d_out doubles as layer scratch

  const int eb = (E + 255) / 256;            // 6250

  // ---- CSR build (once; graph fixed across layers) ----
  k_zero<<<NB, 256, 0, stream>>>(deg, N);
  k_hist<<<eb, 256, 0, stream>>>(eidx, deg);
  k_scan_block<<<NB, 256, 0, stream>>>(deg, excl, bsum);
  k_scan_top<<<1, 512, 0, stream>>>(bsum, boff);
  k_scan_add<<<NB, 256, 0, stream>>>(excl, boff, rowptr, cursor);
  k_scatter<<<eb, 256, 0, stream>>>(eidx, edge_attr, cursor, csr_src, csr_a16);

  // ---- network ----
  k_node_linear<<<N / 32, 256, 0, stream>>>(x, W_node, b_node, h, h16);

  for (int l = 0; l < 3; ++l) {
    k_gather<<<N / 4, 256, 0, stream>>>(rowptr, deg, csr_src, csr_a16,
                                        (const __half2*)h16, W_edge, b_edge, h, sum);
    k_node_update<<<N / 32, 256, 0, stream>>>(
        sum, W_conv + (size_t)l * H * H, b_conv + (size_t)l * H, h, h16);
  }

  k_head<<<N / 8, 256, 0, stream>>>(x, W_node, b_node, h, W_head, b_head, gamma, beta, out);
}

// Round 8
// 1183.059 us; speedup vs baseline: 1.1534x; 1.1534x over previous
//
#include <hip/hip_runtime.h>
#include <hip/hip_fp16.h>

// GraphEncoder: node linear; 3x GINEConv(eps=0, nn=Linear+LeakyReLU); skip; head Linear+LayerNorm.
// R8: k_head rebuilt with 4-node-per-thread W reuse (R7's k_head streamed 96KB of W per node ->
//     L1-refill wall, 298us @ 17% VALU). Now same tiling as k_node_update + shfl-32 LayerNorm.
// edge_index arrives as int32 (harness converts int64 inputs).
constexpr int N      = 100000;
constexpr int E      = 1600000;
constexpr int F_IN   = 64;
constexpr int F_EDGE = 16;
constexpr int H      = 128;
constexpr int NB     = (N + 255) / 256;     // 391 scan blocks
constexpr float NEG  = 0.01f;
constexpr float EPS  = 1e-5f;

typedef _Float16 hv2 __attribute__((ext_vector_type(2)));

// ================= CSR build =================
__global__ __launch_bounds__(256) void k_zero(int* __restrict__ p, int n) {
  int i = blockIdx.x * 256 + threadIdx.x;
  if (i < n) p[i] = 0;
}

__global__ __launch_bounds__(256) void k_hist(const int* __restrict__ eidx, int* __restrict__ deg) {
  int i = blockIdx.x * 256 + threadIdx.x;
  if (i < E) atomicAdd(&deg[eidx[E + i]], 1);
}

__global__ __launch_bounds__(256) void k_scan_block(const int* __restrict__ deg,
    int* __restrict__ excl, int* __restrict__ bsum) {
  __shared__ int s[256];
  int t = threadIdx.x, i = blockIdx.x * 256 + t;
  int v = (i < N) ? deg[i] : 0;
  s[t] = v; __syncthreads();
#pragma unroll
  for (int off = 1; off < 256; off <<= 1) {
    int u = (t >= off) ? s[t - off] : 0;
    __syncthreads();
    s[t] += u;
    __syncthreads();
  }
  if (i < N) excl[i] = s[t] - v;
  if (t == 255) bsum[blockIdx.x] = s[255];
}

__global__ __launch_bounds__(512) void k_scan_top(const int* __restrict__ bsum, int* __restrict__ boff) {
  __shared__ int s[512];
  int t = threadIdx.x;
  int v = (t < NB) ? bsum[t] : 0;
  s[t] = v; __syncthreads();
#pragma unroll
  for (int off = 1; off < 512; off <<= 1) {
    int u = (t >= off) ? s[t - off] : 0;
    __syncthreads();
    s[t] += u;
    __syncthreads();
  }
  if (t < NB) boff[t] = s[t] - v;
}

__global__ __launch_bounds__(256) void k_scan_add(const int* __restrict__ excl,
    const int* __restrict__ boff, int* __restrict__ rowptr, int* __restrict__ cursor) {
  int i = blockIdx.x * 256 + threadIdx.x;
  if (i < N) {
    int r = excl[i] + boff[i >> 8];
    rowptr[i] = r;
    cursor[i] = r;
  }
}

// scatter: CSR-slot src index + edge_attr row converted to fp16 (2x uint4 = 32B/edge)
__global__ __launch_bounds__(256) void k_scatter(const int* __restrict__ eidx,
    const float* __restrict__ edge_attr, int* __restrict__ cursor,
    int* __restrict__ csr_src, uint4* __restrict__ csr_a16) {
  int i = blockIdx.x * 256 + threadIdx.x;
  if (i >= E) return;
  int d = eidx[E + i];
  int pos = atomicAdd(&cursor[d], 1);
  csr_src[pos] = eidx[i];
  const float4* ar = (const float4*)(edge_attr + (size_t)i * F_EDGE);
  float4 f0 = ar[0], f1 = ar[1], f2 = ar[2], f3 = ar[3];
  __half2 hh[8];
  hh[0] = __float22half2_rn(make_float2(f0.x, f0.y));
  hh[1] = __float22half2_rn(make_float2(f0.z, f0.w));
  hh[2] = __float22half2_rn(make_float2(f1.x, f1.y));
  hh[3] = __float22half2_rn(make_float2(f1.z, f1.w));
  hh[4] = __float22half2_rn(make_float2(f2.x, f2.y));
  hh[5] = __float22half2_rn(make_float2(f2.z, f2.w));
  hh[6] = __float22half2_rn(make_float2(f3.x, f3.y));
  hh[7] = __float22half2_rn(make_float2(f3.z, f3.w));
  const uint4* u = (const uint4*)hh;
  csr_a16[2 * (size_t)pos + 0] = u[0];
  csr_a16[2 * (size_t)pos + 1] = u[1];
}

// ================= node linear: h = x @ W_node + b  (32 nodes/block, 4n x 4c per thread) =================
__global__ __launch_bounds__(256) void k_node_linear(
    const float* __restrict__ x, const float* __restrict__ W,
    const float* __restrict__ b, float* __restrict__ h, __half* __restrict__ h16) {
  __shared__ float xs[32][F_IN];             // 8 KB
  int i0 = blockIdx.x * 32;
  {
    const float4* s4 = (const float4*)(x + (size_t)i0 * F_IN);
    float4* t4 = (float4*)xs;
#pragma unroll
    for (int r = 0; r < 2; ++r) t4[threadIdx.x + 256 * r] = s4[threadIdx.x + 256 * r];
  }
  __syncthreads();
  int c0 = (threadIdx.x & 31) * 4;
  int n0 = (threadIdx.x >> 5) * 4;
  float4 bb = *(const float4*)(b + c0);
  float4 acc[4] = {bb, bb, bb, bb};
#pragma unroll 4
  for (int k = 0; k < F_IN; ++k) {
    float4 w4 = *(const float4*)(W + k * H + c0);   // coalesced; reused by 4 nodes
#pragma unroll
    for (int j = 0; j < 4; ++j) {
      float s = xs[n0 + j][k];                      // LDS broadcast
      acc[j].x = fmaf(s, w4.x, acc[j].x);
      acc[j].y = fmaf(s, w4.y, acc[j].y);
      acc[j].z = fmaf(s, w4.z, acc[j].z);
      acc[j].w = fmaf(s, w4.w, acc[j].w);
    }
  }
#pragma unroll
  for (int j = 0; j < 4; ++j) {
    size_t idx = (size_t)(i0 + n0 + j) * H + c0;
    *(float4*)(h + idx) = acc[j];
    __half2* ph = (__half2*)(h16 + idx);
    ph[0] = __float22half2_rn(make_float2(acc[j].x, acc[j].y));
    ph[1] = __float22half2_rn(make_float2(acc[j].z, acc[j].w));
  }
}

// ================= gather: sum[i] = h[i] + sum_in relu(h16[src] + a16@We + be) =================
// 1 wave per node; lane owns channels {2*lane, 2*lane+1}; We as fp16 k-pairs -> v_dot2_f32_f16.
__device__ __forceinline__ void dot16(uint4 A0, uint4 A1,
                                      const hv2* __restrict__ wA, const hv2* __restrict__ wB,
                                      float& tx, float& ty) {
  unsigned u[8] = {A0.x, A0.y, A0.z, A0.w, A1.x, A1.y, A1.z, A1.w};
#pragma unroll
  for (int j = 0; j < 8; ++j) {
    hv2 a = __builtin_bit_cast(hv2, u[j]);
    tx = __builtin_amdgcn_fdot2(a, wA[j], tx, false);
    ty = __builtin_amdgcn_fdot2(a, wB[j], ty, false);
  }
}

__global__ __launch_bounds__(256) void k_gather(
    const int* __restrict__ rowptr, const int* __restrict__ deg,
    const int* __restrict__ csr_src, const uint4* __restrict__ csr_a16,
    const __half2* __restrict__ h16, const float* __restrict__ We,
    const float* __restrict__ be, const float* __restrict__ h,
    float* __restrict__ sum) {
  int lane = threadIdx.x & 63;
  int node = (blockIdx.x * 256 + threadIdx.x) >> 6;
  if (node >= N) return;
  int c0 = 2 * lane;
  hv2 wA[8], wB[8];                          // We columns c0,c0+1 packed as k-pairs
#pragma unroll
  for (int j = 0; j < 8; ++j) {
    hv2 a, bq;
    a[0]  = (_Float16)We[(2 * j) * H + c0];
    a[1]  = (_Float16)We[(2 * j + 1) * H + c0];
    bq[0] = (_Float16)We[(2 * j) * H + c0 + 1];
    bq[1] = (_Float16)We[(2 * j + 1) * H + c0 + 1];
    wA[j] = a; wB[j] = bq;
  }
  float2 bias = ((const float2*)be)[lane];
  float2 acc = ((const float2*)(h + (size_t)node * H))[lane];   // self term, fp32
  int p0 = rowptr[node];
  int pend = p0 + deg[node];
  int p = p0;
  for (; p + 2 <= pend; p += 2) {
    int s0 = csr_src[p];
    int s1 = csr_src[p + 1];
    __half2 g0 = h16[(size_t)s0 * 64 + lane];   // random 256B/wave
    __half2 g1 = h16[(size_t)s1 * 64 + lane];
    uint4 A0 = csr_a16[2 * (size_t)p + 0];      // wave-uniform sequential stream
    uint4 A1 = csr_a16[2 * (size_t)p + 1];
    uint4 B0 = csr_a16[2 * (size_t)p + 2];
    uint4 B1 = csr_a16[2 * (size_t)p + 3];
    float t0x = bias.x, t0y = bias.y;
    float t1x = bias.x, t1y = bias.y;
    dot16(A0, A1, wA, wB, t0x, t0y);
    dot16(B0, B1, wA, wB, t1x, t1y);
    float2 gf0 = __half22float2(g0);
    float2 gf1 = __half22float2(g1);
    acc.x += fmaxf(gf0.x + t0x, 0.f) + fmaxf(gf1.x + t1x, 0.f);
    acc.y += fmaxf(gf0.y + t0y, 0.f) + fmaxf(gf1.y + t1y, 0.f);
  }
  for (; p < pend; ++p) {
    int s = csr_src[p];
    __half2 g = h16[(size_t)s * 64 + lane];
    uint4 A0 = csr_a16[2 * (size_t)p + 0];
    uint4 A1 = csr_a16[2 * (size_t)p + 1];
    float tx = bias.x, ty = bias.y;
    dot16(A0, A1, wA, wB, tx, ty);
    float2 gf = __half22float2(g);
    acc.x += fmaxf(gf.x + tx, 0.f);
    acc.y += fmaxf(gf.y + ty, 0.f);
  }
  ((float2*)sum)[(size_t)node * 64 + lane] = acc;
}

// ================= node update: h = leaky_relu(sum @ W_conv[l] + b)  (32 nodes/block) =================
__global__ __launch_bounds__(256) void k_node_update(
    const float* __restrict__ sum, const float* __restrict__ W,
    const float* __restrict__ b, float* __restrict__ hout, __half* __restrict__ h16) {
  __shared__ float t[32][H];                 // 16 KB
  int i0 = blockIdx.x * 32;
  {
    const float4* s4 = (const float4*)(sum + (size_t)i0 * H);
    float4* t4 = (float4*)t;
#pragma unroll
    for (int r = 0; r < 4; ++r) t4[threadIdx.x + 256 * r] = s4[threadIdx.x + 256 * r];
  }
  __syncthreads();
  int c0 = (threadIdx.x & 31) * 4;
  int n0 = (threadIdx.x >> 5) * 4;
  float4 bb = *(const float4*)(b + c0);
  float4 acc[4] = {bb, bb, bb, bb};
#pragma unroll 4
  for (int k = 0; k < H; ++k) {
    float4 w4 = *(const float4*)(W + k * H + c0);   // coalesced; reused by 4 nodes
#pragma unroll
    for (int j = 0; j < 4; ++j) {
      float s = t[n0 + j][k];                       // LDS broadcast
      acc[j].x = fmaf(s, w4.x, acc[j].x);
      acc[j].y = fmaf(s, w4.y, acc[j].y);
      acc[j].z = fmaf(s, w4.z, acc[j].z);
      acc[j].w = fmaf(s, w4.w, acc[j].w);
    }
  }
#pragma unroll
  for (int j = 0; j < 4; ++j) {
    float4 a = acc[j];
    a.x = a.x >= 0.f ? a.x : NEG * a.x;
    a.y = a.y >= 0.f ? a.y : NEG * a.y;
    a.z = a.z >= 0.f ? a.z : NEG * a.z;
    a.w = a.w >= 0.f ? a.w : NEG * a.w;
    size_t idx = (size_t)(i0 + n0 + j) * H + c0;
    *(float4*)(hout + idx) = a;
    __half2* ph = (__half2*)(h16 + idx);
    ph[0] = __float22half2_rn(make_float2(a.x, a.y));
    ph[1] = __float22half2_rn(make_float2(a.z, a.w));
  }
}

// ================= head: skip recomputed; y = (skip+h)@W_head + b; LayerNorm  (32 nodes/block) =================
__global__ __launch_bounds__(256) void k_head(
    const float* __restrict__ x, const float* __restrict__ Wn,
    const float* __restrict__ bn, const float* __restrict__ hfin,
    const float* __restrict__ W, const float* __restrict__ b,
    const float* __restrict__ gamma, const float* __restrict__ beta,
    float* __restrict__ out) {
  __shared__ float xs[32][F_IN];             // 8 KB
  __shared__ float t[32][H];                 // 16 KB
  int i0 = blockIdx.x * 32;
  {
    const float4* s4 = (const float4*)(x + (size_t)i0 * F_IN);
    float4* t4 = (float4*)xs;
#pragma unroll
    for (int r = 0; r < 2; ++r) t4[threadIdx.x + 256 * r] = s4[threadIdx.x + 256 * r];
  }
  __syncthreads();
  int c0 = (threadIdx.x & 31) * 4;
  int n0 = (threadIdx.x >> 5) * 4;
  // skip = x @ W_node + b_node, 4 nodes x 4 channels, W reused across nodes
  {
    float4 bb = *(const float4*)(bn + c0);
    float4 acc[4] = {bb, bb, bb, bb};
#pragma unroll 4
    for (int k = 0; k < F_IN; ++k) {
      float4 w4 = *(const float4*)(Wn + k * H + c0);
#pragma unroll
      for (int j = 0; j < 4; ++j) {
        float s = xs[n0 + j][k];                    // LDS broadcast
        acc[j].x = fmaf(s, w4.x, acc[j].x);
        acc[j].y = fmaf(s, w4.y, acc[j].y);
        acc[j].z = fmaf(s, w4.z, acc[j].z);
        acc[j].w = fmaf(s, w4.w, acc[j].w);
      }
    }
#pragma unroll
    for (int j = 0; j < 4; ++j) {
      float4 hf = *(const float4*)(hfin + (size_t)(i0 + n0 + j) * H + c0);
      acc[j].x += hf.x; acc[j].y += hf.y; acc[j].z += hf.z; acc[j].w += hf.w;
      *(float4*)&t[n0 + j][c0] = acc[j];
    }
  }
  __syncthreads();
  float4 bh = *(const float4*)(b + c0);
  float4 acc[4] = {bh, bh, bh, bh};
#pragma unroll 4
  for (int k = 0; k < H; ++k) {
    float4 w4 = *(const float4*)(W + k * H + c0);   // coalesced; reused by 4 nodes
#pragma unroll
    for (int j = 0; j < 4; ++j) {
      float s = t[n0 + j][k];                       // LDS broadcast
      acc[j].x = fmaf(s, w4.x, acc[j].x);
      acc[j].y = fmaf(s, w4.y, acc[j].y);
      acc[j].z = fmaf(s, w4.z, acc[j].z);
      acc[j].w = fmaf(s, w4.w, acc[j].w);
    }
  }
  // LayerNorm: channels of node n0+j live in acc[j] across the 32 lanes of this half-wave
  float4 g4 = *(const float4*)(gamma + c0);
  float4 b4 = *(const float4*)(beta + c0);
#pragma unroll
  for (int j = 0; j < 4; ++j) {
    float S  = acc[j].x + acc[j].y + acc[j].z + acc[j].w;
    float S2 = acc[j].x * acc[j].x + acc[j].y * acc[j].y
             + acc[j].z * acc[j].z + acc[j].w * acc[j].w;
#pragma unroll
    for (int off = 16; off > 0; off >>= 1) {
      S  += __shfl_down(S, off, 32);
      S2 += __shfl_down(S2, off, 32);
    }
    S  = __shfl(S, 0, 32);
    S2 = __shfl(S2, 0, 32);
    float mu  = S * (1.f / H);
    float var = S2 * (1.f / H) - mu * mu;
    float inv = rsqrtf(var + EPS);
    float4 o;
    o.x = (acc[j].x - mu) * inv * g4.x + b4.x;
    o.y = (acc[j].y - mu) * inv * g4.y + b4.y;
    o.z = (acc[j].z - mu) * inv * g4.z + b4.z;
    o.w = (acc[j].w - mu) * inv * g4.w + b4.w;
    *(float4*)(out + (size_t)(i0 + n0 + j) * H + c0) = o;
  }
}

extern "C" void kernel_launch(void* const* d_in, const int* in_sizes, int n_in,
                              void* d_out, int out_size, void* d_ws, size_t ws_size,
                              hipStream_t stream) {
  const float* x         = (const float*)d_in[0];
  const float* edge_attr = (const float*)d_in[1];
  const int*   eidx      = (const int*)d_in[2];      // int32 (harness-converted)
  const float* W_node    = (const float*)d_in[3];
  const float* b_node    = (const float*)d_in[4];
  const float* W_edge    = (const float*)d_in[5];
  const float* b_edge    = (const float*)d_in[6];
  const float* W_conv    = (const float*)d_in[7];    // [3,128,128]
  const float* b_conv    = (const float*)d_in[8];    // [3,128]
  const float* W_head    = (const float*)d_in[9];
  const float* b_head    = (const float*)d_in[10];
  const float* gamma     = (const float*)d_in[11];
  const float* beta      = (const float*)d_in[12];
  float* out = (float*)d_out;

  // ---- workspace layout (~136.2 MB) ----
  size_t S = (size_t)N * H;                  // 12.8M floats = 51.2 MB
  float*   h       = (float*)d_ws;           // 51.2 MB
  uint4*   csr_a16 = (uint4*)(h + S);        // 51.2 MB (E x 32B)
  __half*  h16     = (__half*)(csr_a16 + 2 * (size_t)E);  // 25.6 MB
  int*     csr_src = (int*)(h16 + S);        // 6.4 MB
  int*     deg     = csr_src + E;
  int*     excl    = deg + N;
  int*     rowptr  = excl + N;
  int*     cursor  = rowptr + N;
  int*     bsum    = cursor + N;
  int*     boff    = bsum + 512;
  float*   sum     = out;                    // d_out doubles as layer scratch

  const int eb = (E + 255) / 256;            // 6250

  // ---- CSR build (once; graph fixed across layers) ----
  k_zero<<<NB, 256, 0, stream>>>(deg, N);
  k_hist<<<eb, 256, 0, stream>>>(eidx, deg);
  k_scan_block<<<NB, 256, 0, stream>>>(deg, excl, bsum);
  k_scan_top<<<1, 512, 0, stream>>>(bsum, boff);
  k_scan_add<<<NB, 256, 0, stream>>>(excl, boff, rowptr, cursor);
  k_scatter<<<eb, 256, 0, stream>>>(eidx, edge_attr, cursor, csr_src, csr_a16);

  // ---- network ----
  k_node_linear<<<N / 32, 256, 0, stream>>>(x, W_node, b_node, h, h16);

  for (int l = 0; l < 3; ++l) {
    k_gather<<<N / 4, 256, 0, stream>>>(rowptr, deg, csr_src, csr_a16,
                                        (const __half2*)h16, W_edge, b_edge, h, sum);
    k_node_update<<<N / 32, 256, 0, stream>>>(
        sum, W_conv + (size_t)l * H * H, b_conv + (size_t)l * H, h, h16);
  }

  k_head<<<N / 32, 256, 0, stream>>>(x, W_node, b_node, h, W_head, b_head, gamma, beta, out);
}